// Round 3
// baseline (468.023 us; speedup 1.0000x reference)
//
#include <hip/hip_runtime.h>

// TemporalXORReservoirNetwork — R3: write-contiguity restructure.
//
// R2 post-mortem: barrier removal changed nothing (142 -> 155 us). Kernel
// writes 419 MB at only 2.8 TB/s while the harness's fillBufferAligned hits
// 6.1 TB/s in the same graph => limited by stream shape (8 KB runs strided
// 2 MB from 256 blocks), not sync or in-flight count.
//
// R3: two kernels. A: uncoupled 200-step scan per (b,n), checkpoints V every
// 8 steps into ws (25 x 2 MB) + per-b spike flag (spikes never occur; flag
// gates a coupled fallback). B: 800 blocks = 25 t-chunks x 32 b-groups; each
// re-simulates 8 steps for 8 b-rows from the checkpoint and streams 8 x 64 KB
// contiguous, globally ascending — fill-like pattern.
// Floor: 419 MB write + 50 MB ckpt r/w ~= 80 us at ~6 TB/s.

#define SEQ    200
#define BATCH  256
#define NRES   2048
#define K_CHK  8
#define C_CHK  25            // SEQ / K_CHK
#define M_SUB  32            // b-groups per chunk
#define BPB    8             // BATCH / M_SUB
#define BETA_F 0.9f

#define WS_CKPT_F4OFF 256    // flags: 256 ints (1 KB), then ckpt floats
#define WS_NEED (1024 + (size_t)C_CHK * BATCH * NRES * 4)

// ---------------- Kernel A: uncoupled scan + checkpoints + flags ----------------
__global__ __launch_bounds__(512, 1) void snn_scan_kernel(
    const float* __restrict__ x, const float* __restrict__ Win,
    float* __restrict__ ws)
{
    const int b = blockIdx.x, tid = threadIdx.x, n0 = tid << 2;
    __shared__ float4 sx[SEQ];
    __shared__ int wor[8];

    for (int t = tid; t < SEQ; t += 512) {
        const float* p = x + (size_t)t * (BATCH * 3) + b * 3;
        sx[t] = make_float4(p[0], p[1], p[2], 0.f);
    }
    const float* wp = Win + (size_t)n0 * 3;     // 12 contiguous floats, 16B-aligned
    const float4 wa = *(const float4*)wp;
    const float4 wb = *(const float4*)(wp + 4);
    const float4 wc = *(const float4*)(wp + 8);
    const float wi[4][3] = {{wa.x, wa.y, wa.z}, {wa.w, wb.x, wb.y},
                            {wb.z, wb.w, wc.x}, {wc.y, wc.z, wc.w}};
    float V[4] = {0.f, 0.f, 0.f, 0.f};
    bool spiked = false;
    float* ck = ws + WS_CKPT_F4OFF;
    __syncthreads();

    for (int t = 0; t < SEQ; ++t) {
        if ((t & 7) == 0) {   // state ENTERING step t=8c
            const int c = t >> 3;
            *(float4*)(ck + (size_t)(c * BATCH + b) * NRES + n0) =
                make_float4(V[0], V[1], V[2], V[3]);
        }
        const float4 xv = sx[t];
        #pragma unroll
        for (int j = 0; j < 4; ++j) {
            const float cur = fmaf(xv.x, wi[j][0], fmaf(xv.y, wi[j][1], xv.z * wi[j][2]));
            V[j] = fmaf(BETA_F, V[j], cur);
            const bool s = (V[j] >= 1.0f);
            spiked |= s;
            V[j] = s ? 0.f : V[j];
        }
    }
    const unsigned long long bal = __ballot(spiked);
    if ((tid & 63) == 0) wor[tid >> 6] = (bal != 0ull) ? 1 : 0;
    __syncthreads();
    if (tid == 0) {
        int f = 0;
        #pragma unroll
        for (int i = 0; i < 8; ++i) f |= wor[i];
        ((int*)ws)[b] = f;
    }
}

// ---------------- Kernel B: contiguous writer (+ coupled fallback) ----------------
__global__ __launch_bounds__(512, 1) void snn_write_kernel(
    const float* __restrict__ x, const float* __restrict__ W,
    const float* __restrict__ Win, const float* __restrict__ Wout,
    const float* __restrict__ ws, float* __restrict__ out)
{
    const int tid = threadIdx.x, lane = tid & 63, wid = tid >> 6;
    __shared__ int sflag;
    __shared__ float4 sxc[K_CHK][BPB];
    __shared__ float4 sx[SEQ];                    // fallback only
    __shared__ unsigned long long smask[2][32];   // fallback only
    __shared__ int scum[2];                       // fallback only
    __shared__ float red[2][8];                   // fallback only

    if (tid == 0) sflag = 0;
    __syncthreads();
    {
        const int f = (tid < BATCH) ? ((const int*)ws)[tid] : 0;
        if (__ballot(f != 0)) { if (lane == 0) atomicOr(&sflag, 1); }
    }
    __syncthreads();

    if (!sflag) {
        // -------- fast path: contiguous streaming writes --------
        const int c  = blockIdx.x >> 5;       // t-chunk 0..24
        const int m  = blockIdx.x & 31;       // b-group 0..31
        const int b0 = m * BPB;
        const int t0 = c * K_CHK;
        const int n0 = tid << 2;

        if (tid < K_CHK * BPB) {
            const int tl = tid >> 3, bl = tid & 7;
            const float* p = x + (size_t)(t0 + tl) * (BATCH * 3) + (b0 + bl) * 3;
            sxc[tl][bl] = make_float4(p[0], p[1], p[2], 0.f);
        }
        const float* wp = Win + (size_t)n0 * 3;
        const float4 wa = *(const float4*)wp;
        const float4 wb = *(const float4*)(wp + 4);
        const float4 wc = *(const float4*)(wp + 8);
        const float wi[4][3] = {{wa.x, wa.y, wa.z}, {wa.w, wb.x, wb.y},
                                {wb.z, wb.w, wc.x}, {wc.y, wc.z, wc.w}};
        __syncthreads();

        unsigned sbits[BPB];
        const float* ck = ws + WS_CKPT_F4OFF;
        #pragma unroll
        for (int g = 0; g < BPB; ++g) {       // g == local b index
            const float4 V4 = *(const float4*)(ck + (size_t)(c * BATCH + b0 + g) * NRES + n0);
            float V[4] = {V4.x, V4.y, V4.z, V4.w};
            unsigned bits = 0u;
            #pragma unroll
            for (int tl = 0; tl < K_CHK; ++tl) {
                const float4 xv = sxc[tl][g];
                #pragma unroll
                for (int j = 0; j < 4; ++j) {
                    const float cur = fmaf(xv.x, wi[j][0],
                                      fmaf(xv.y, wi[j][1], xv.z * wi[j][2]));
                    V[j] = fmaf(BETA_F, V[j], cur);
                    const bool s = (V[j] >= 1.0f);
                    bits |= (unsigned)s << (tl * 4 + j);
                    V[j] = s ? 0.f : V[j];
                }
            }
            sbits[g] = bits;
        }
        // burst store: ascending t, ascending b => dense ascending 64 KB window
        #pragma unroll
        for (int tl = 0; tl < K_CHK; ++tl) {
            float* po = out + ((size_t)(t0 + tl) * BATCH + b0) * NRES + n0;
            #pragma unroll
            for (int g = 0; g < BPB; ++g) {
                const unsigned bt = sbits[g] >> (tl * 4);
                *(float4*)(po + (size_t)g * NRES) =
                    make_float4((bt & 1u) ? 1.f : 0.f, (bt & 2u) ? 1.f : 0.f,
                                (bt & 4u) ? 1.f : 0.f, (bt & 8u) ? 1.f : 0.f);
            }
        }
        if (blockIdx.x == 0) out[(size_t)SEQ * BATCH * NRES + tid] = 0.f;  // logits == 0
        return;
    }

    // -------- fallback: fully-coupled re-run (never taken in practice) --------
    if (blockIdx.x >= BATCH) return;
    const int b = blockIdx.x;
    const int n0 = tid << 2;

    for (int t = tid; t < SEQ; t += 512) {
        const float* p = x + (size_t)t * (BATCH * 3) + b * 3;
        sx[t] = make_float4(p[0], p[1], p[2], 0.f);
    }
    if (tid < 64) smask[tid >> 5][tid & 31] = 0ull;
    if (tid < 2)  scum[tid] = 0;
    const float* wp = Win + (size_t)n0 * 3;
    const float4 wa = *(const float4*)wp;
    const float4 wb = *(const float4*)(wp + 4);
    const float4 wc = *(const float4*)(wp + 8);
    const float wi[4][3] = {{wa.x, wa.y, wa.z}, {wa.w, wb.x, wb.y},
                            {wb.z, wb.w, wc.x}, {wc.y, wc.z, wc.w}};
    float V[4] = {0.f, 0.f, 0.f, 0.f};
    int cnt[4] = {0, 0, 0, 0};
    __syncthreads();

    int seen[2] = {0, 0};
    float* po = out + (size_t)b * NRES + n0;
    for (int t = 0; t < SEQ; ++t) {
        const int curp = t & 1, prev = curp ^ 1;
        float rec[4] = {0.f, 0.f, 0.f, 0.f};
        const int csp = scum[prev];
        if (csp != seen[prev]) {          // spikes at t-1: gather W rows
            seen[prev] = csp;
            #pragma unroll 1
            for (int u = 0; u < 32; ++u) {
                unsigned long long mm = smask[prev][u];
                const int kbase = ((u >> 2) << 8) + (u & 3);
                while (mm) {
                    const int l = __builtin_ctzll(mm);
                    mm &= mm - 1;
                    const int k = kbase + (l << 2);
                    const float4 wv = *(const float4*)(W + (size_t)k * NRES + n0);
                    rec[0] += wv.x; rec[1] += wv.y; rec[2] += wv.z; rec[3] += wv.w;
                }
            }
        }
        const float4 xv = sx[t];
        float4 sp;
        unsigned long long bj[4];
        #pragma unroll
        for (int j = 0; j < 4; ++j) {
            const float cur = fmaf(xv.x, wi[j][0],
                              fmaf(xv.y, wi[j][1], xv.z * wi[j][2])) + rec[j];
            V[j] = fmaf(BETA_F, V[j], cur);
            const bool s = (V[j] >= 1.0f);
            V[j] = s ? 0.f : V[j];
            ((float*)&sp)[j] = s ? 1.f : 0.f;
            if (t >= SEQ - 10) cnt[j] += (int)s;
            bj[j] = __ballot(s);
        }
        *(float4*)po = sp;
        po += BATCH * NRES;
        if (lane == 0) {
            int wpc = 0;
            #pragma unroll
            for (int j = 0; j < 4; ++j) {
                smask[curp][(wid << 2) + j] = bj[j];
                wpc += __popcll(bj[j]);
            }
            if (wpc) atomicAdd(&scum[curp], wpc);
        }
        __syncthreads();
    }
    const float4 w0 = *(const float4*)(Wout + n0);
    const float4 w1 = *(const float4*)(Wout + NRES + n0);
    float p0 = cnt[0] * 0.1f * w0.x + cnt[1] * 0.1f * w0.y +
               cnt[2] * 0.1f * w0.z + cnt[3] * 0.1f * w0.w;
    float p1 = cnt[0] * 0.1f * w1.x + cnt[1] * 0.1f * w1.y +
               cnt[2] * 0.1f * w1.z + cnt[3] * 0.1f * w1.w;
    #pragma unroll
    for (int off = 32; off > 0; off >>= 1) {
        p0 += __shfl_down(p0, off);
        p1 += __shfl_down(p1, off);
    }
    if (lane == 0) { red[0][wid] = p0; red[1][wid] = p1; }
    __syncthreads();
    if (tid == 0) {
        float q0 = 0.f, q1 = 0.f;
        #pragma unroll
        for (int i = 0; i < 8; ++i) { q0 += red[0][i]; q1 += red[1][i]; }
        const size_t loff = (size_t)SEQ * BATCH * NRES;
        out[loff + b * 2 + 0] = q0;
        out[loff + b * 2 + 1] = q1;
    }
}

// ---------------- mono fallback (only if ws too small) ----------------
__global__ __launch_bounds__(512, 1) void snn_mono_kernel(
    const float* __restrict__ x, const float* __restrict__ W,
    const float* __restrict__ Win, const float* __restrict__ Wout,
    float* __restrict__ out)
{
    const int b = blockIdx.x, tid = threadIdx.x, lane = tid & 63, wid = tid >> 6;
    const int n0 = tid << 2;
    __shared__ float4 sx[SEQ];
    __shared__ unsigned long long smask[2][32];
    __shared__ int scum[2];
    __shared__ float red[2][8];
    __shared__ int anyflag;

    for (int t = tid; t < SEQ; t += 512) {
        const float* p = x + (size_t)t * (BATCH * 3) + b * 3;
        sx[t] = make_float4(p[0], p[1], p[2], 0.f);
    }
    if (tid == 0) anyflag = 0;
    const float* wp = Win + (size_t)n0 * 3;
    const float4 wa = *(const float4*)wp;
    const float4 wb = *(const float4*)(wp + 4);
    const float4 wc = *(const float4*)(wp + 8);
    const float wi[4][3] = {{wa.x, wa.y, wa.z}, {wa.w, wb.x, wb.y},
                            {wb.z, wb.w, wc.x}, {wc.y, wc.z, wc.w}};
    float V[4] = {0.f, 0.f, 0.f, 0.f};
    int cnt[4] = {0, 0, 0, 0};
    __syncthreads();
    {
        float* po = out + (size_t)b * NRES + n0;
        bool spiked = false;
        for (int t = 0; t < SEQ; ++t) {
            const float4 xv = sx[t];
            float4 sp;
            #pragma unroll
            for (int j = 0; j < 4; ++j) {
                const float cur = fmaf(xv.x, wi[j][0], fmaf(xv.y, wi[j][1], xv.z * wi[j][2]));
                V[j] = fmaf(BETA_F, V[j], cur);
                const bool s = (V[j] >= 1.0f);
                spiked |= s;
                V[j] = s ? 0.f : V[j];
                ((float*)&sp)[j] = s ? 1.f : 0.f;
                if (t >= SEQ - 10) cnt[j] += (int)s;
            }
            *(float4*)po = sp;
            po += BATCH * NRES;
        }
        if (lane == 0 && __ballot(spiked) != 0ull) atomicOr(&anyflag, 1);
    }
    __syncthreads();
    if (anyflag) {
        #pragma unroll
        for (int j = 0; j < 4; ++j) { V[j] = 0.f; cnt[j] = 0; }
        if (tid < 64) smask[tid >> 5][tid & 31] = 0ull;
        if (tid < 2)  scum[tid] = 0;
        __syncthreads();
        int seen[2] = {0, 0};
        float* po = out + (size_t)b * NRES + n0;
        for (int t = 0; t < SEQ; ++t) {
            const int curp = t & 1, prev = curp ^ 1;
            float rec[4] = {0.f, 0.f, 0.f, 0.f};
            const int csp = scum[prev];
            if (csp != seen[prev]) {
                seen[prev] = csp;
                #pragma unroll 1
                for (int u = 0; u < 32; ++u) {
                    unsigned long long mm = smask[prev][u];
                    const int kbase = ((u >> 2) << 8) + (u & 3);
                    while (mm) {
                        const int l = __builtin_ctzll(mm);
                        mm &= mm - 1;
                        const int k = kbase + (l << 2);
                        const float4 wv = *(const float4*)(W + (size_t)k * NRES + n0);
                        rec[0] += wv.x; rec[1] += wv.y; rec[2] += wv.z; rec[3] += wv.w;
                    }
                }
            }
            const float4 xv = sx[t];
            float4 sp;
            unsigned long long bj[4];
            #pragma unroll
            for (int j = 0; j < 4; ++j) {
                const float cur = fmaf(xv.x, wi[j][0],
                                  fmaf(xv.y, wi[j][1], xv.z * wi[j][2])) + rec[j];
                V[j] = fmaf(BETA_F, V[j], cur);
                const bool s = (V[j] >= 1.0f);
                V[j] = s ? 0.f : V[j];
                ((float*)&sp)[j] = s ? 1.f : 0.f;
                if (t >= SEQ - 10) cnt[j] += (int)s;
                bj[j] = __ballot(s);
            }
            *(float4*)po = sp;
            po += BATCH * NRES;
            if (lane == 0) {
                int wpc = 0;
                #pragma unroll
                for (int j = 0; j < 4; ++j) {
                    smask[curp][(wid << 2) + j] = bj[j];
                    wpc += __popcll(bj[j]);
                }
                if (wpc) atomicAdd(&scum[curp], wpc);
            }
            __syncthreads();
        }
    }
    const float4 w0 = *(const float4*)(Wout + n0);
    const float4 w1 = *(const float4*)(Wout + NRES + n0);
    float p0 = cnt[0] * 0.1f * w0.x + cnt[1] * 0.1f * w0.y +
               cnt[2] * 0.1f * w0.z + cnt[3] * 0.1f * w0.w;
    float p1 = cnt[0] * 0.1f * w1.x + cnt[1] * 0.1f * w1.y +
               cnt[2] * 0.1f * w1.z + cnt[3] * 0.1f * w1.w;
    #pragma unroll
    for (int off = 32; off > 0; off >>= 1) {
        p0 += __shfl_down(p0, off);
        p1 += __shfl_down(p1, off);
    }
    if (lane == 0) { red[0][wid] = p0; red[1][wid] = p1; }
    __syncthreads();
    if (tid == 0) {
        float q0 = 0.f, q1 = 0.f;
        #pragma unroll
        for (int i = 0; i < 8; ++i) { q0 += red[0][i]; q1 += red[1][i]; }
        const size_t loff = (size_t)SEQ * BATCH * NRES;
        out[loff + b * 2 + 0] = q0;
        out[loff + b * 2 + 1] = q1;
    }
}

extern "C" void kernel_launch(void* const* d_in, const int* in_sizes, int n_in,
                              void* d_out, int out_size, void* d_ws, size_t ws_size,
                              hipStream_t stream) {
    const float* x    = (const float*)d_in[0];
    const float* W    = (const float*)d_in[1];
    const float* Win  = (const float*)d_in[2];
    const float* Wout = (const float*)d_in[3];
    float* out = (float*)d_out;
    if (ws_size >= WS_NEED) {
        float* ws = (float*)d_ws;
        hipLaunchKernelGGL(snn_scan_kernel, dim3(BATCH), dim3(512), 0, stream,
                           x, Win, ws);
        hipLaunchKernelGGL(snn_write_kernel, dim3(C_CHK * M_SUB), dim3(512), 0, stream,
                           x, W, Win, Wout, ws, out);
    } else {
        hipLaunchKernelGGL(snn_mono_kernel, dim3(BATCH), dim3(512), 0, stream,
                           x, W, Win, Wout, out);
    }
}

// Round 5
// 419.539 us; speedup vs baseline: 1.1156x; 1.1156x over previous
//
#include <hip/hip_runtime.h>

// TemporalXORReservoirNetwork — R5: nontemporal stores (R4 compile-fixed).
//
// R1-R3 evidence: write pattern, barriers, wave count ~irrelevant; every
// variant sticks at ~2.8-3 TB/s effective write BW = HALF the 6.26 TB/s the
// poison fill reaches in the same graph. Theory: store-miss RFO — L2 fetches
// each 64B line from HBM before the write, doubling traffic (419 MB written
// -> 838 MB moved -> 142 us @5.9 TB/s, matches R1). The rocclr fill shows
// ~zero FETCH_SIZE on 1.68 GB of stores => nt (no-allocate) streaming.
// R5 = R2 structure + __builtin_nontemporal_store via native ext_vector_type
// (the HIP_vector_type struct is rejected by the builtin).
// Predicted: kernel ~70-80 us, bench ~340-350 us, FETCH ~1 MB.

#define SEQ    200
#define BATCH  256
#define NRES   2048
#define NTHR   512          // 8 waves; 4 neurons/thread -> float4 stores
#define BETA_F 0.9f

typedef float f4_t __attribute__((ext_vector_type(4)));  // native vec: nt-store OK

__global__ __launch_bounds__(NTHR, 1) void snn_reservoir_kernel(
    const float* __restrict__ x,     // [200, 256, 3]
    const float* __restrict__ W,     // [2048, 2048]  (row k -> col n)
    const float* __restrict__ Win,   // [2048, 3]
    const float* __restrict__ Wout,  // [2, 2048]
    float* __restrict__ out)         // spk_rec [200,256,2048] then logits [256,2]
{
    const int b    = blockIdx.x;
    const int tid  = threadIdx.x;
    const int lane = tid & 63;
    const int wid  = tid >> 6;        // 0..7
    const int n0   = tid << 2;        // neurons n0..n0+3

    __shared__ float4 sx[SEQ];                    // x[:, b, :]
    __shared__ unsigned long long smask[2][32];   // slow path: spike bitmask
    __shared__ int   scum[2];                     // slow path: cumulative spike count
    __shared__ float red[2][8];
    __shared__ int   anyflag;

    for (int t = tid; t < SEQ; t += NTHR) {
        const float* p = x + (size_t)t * (BATCH * 3) + b * 3;
        sx[t] = make_float4(p[0], p[1], p[2], 0.0f);
    }
    if (tid == 0) anyflag = 0;

    // Input weights for 4 neurons (12 contiguous, 16B-aligned floats)
    const float* wp = Win + (size_t)n0 * 3;
    const float4 wa = *(const float4*)wp;
    const float4 wb = *(const float4*)(wp + 4);
    const float4 wc = *(const float4*)(wp + 8);
    const float wi[4][3] = {{wa.x, wa.y, wa.z}, {wa.w, wb.x, wb.y},
                            {wb.z, wb.w, wc.x}, {wc.y, wc.z, wc.w}};

    float V[4]  = {0.f, 0.f, 0.f, 0.f};
    int   cnt[4] = {0, 0, 0, 0};

    __syncthreads();   // staging + anyflag visible

    // ---------------- FAST PATH: uncoupled, barrier-free, nt stores ----------------
    {
        float* po = out + (size_t)b * NRES + n0;
        bool spiked = false;
        #pragma unroll 2
        for (int t = 0; t < SEQ; ++t) {
            const float4 xv = sx[t];
            f4_t sp;
            #pragma unroll
            for (int j = 0; j < 4; ++j) {
                const float cur = fmaf(xv.x, wi[j][0],
                                  fmaf(xv.y, wi[j][1], xv.z * wi[j][2]));
                V[j] = fmaf(BETA_F, V[j], cur);
                const bool s = (V[j] >= 1.0f);
                spiked |= s;
                V[j] = s ? 0.f : V[j];
                sp[j] = s ? 1.f : 0.f;
                if (t >= SEQ - 10) cnt[j] += (int)s;
            }
            __builtin_nontemporal_store(sp, (f4_t*)po);   // nt: no-allocate, no RFO
            po += BATCH * NRES;
        }
        const unsigned long long bal = __ballot(spiked);
        if (lane == 0 && bal != 0ull) atomicOr(&anyflag, 1);
    }
    __syncthreads();

    // ---------------- SLOW PATH: coupled re-run (never taken) ----------------
    if (anyflag) {
        #pragma unroll
        for (int j = 0; j < 4; ++j) { V[j] = 0.f; cnt[j] = 0; }
        if (tid < 64) smask[tid >> 5][tid & 31] = 0ull;
        if (tid < 2)  scum[tid] = 0;
        __syncthreads();

        int seen[2] = {0, 0};
        float* po = out + (size_t)b * NRES + n0;
        for (int t = 0; t < SEQ; ++t) {
            const int curp = t & 1, prev = curp ^ 1;
            float rec[4] = {0.f, 0.f, 0.f, 0.f};
            const int c = scum[prev];
            if (c != seen[prev]) {            // spikes at step t-1: gather W rows
                seen[prev] = c;
                #pragma unroll 1
                for (int u = 0; u < 32; ++u) {
                    unsigned long long m = smask[prev][u];
                    const int kbase = ((u >> 2) << 8) + (u & 3);
                    while (m) {
                        const int l = __builtin_ctzll(m);
                        m &= m - 1;
                        const int k = kbase + (l << 2);
                        const float4 wv = *(const float4*)(W + (size_t)k * NRES + n0);
                        rec[0] += wv.x; rec[1] += wv.y;
                        rec[2] += wv.z; rec[3] += wv.w;
                    }
                }
            }
            const float4 xv = sx[t];
            float4 sp;
            unsigned long long bj[4];
            #pragma unroll
            for (int j = 0; j < 4; ++j) {
                const float cur = fmaf(xv.x, wi[j][0],
                                  fmaf(xv.y, wi[j][1], xv.z * wi[j][2])) + rec[j];
                V[j] = fmaf(BETA_F, V[j], cur);
                const bool s = (V[j] >= 1.0f);
                V[j] = s ? 0.f : V[j];
                ((float*)&sp)[j] = s ? 1.f : 0.f;
                if (t >= SEQ - 10) cnt[j] += (int)s;
                bj[j] = __ballot(s);
            }
            *(float4*)po = sp;
            po += BATCH * NRES;
            if (lane == 0) {
                int wpc = 0;
                #pragma unroll
                for (int j = 0; j < 4; ++j) {
                    smask[curp][(wid << 2) + j] = bj[j];
                    wpc += __popcll(bj[j]);
                }
                if (wpc) atomicAdd(&scum[curp], wpc);
            }
            __syncthreads();
        }
    }

    // ---------------- logits epilogue ----------------
    const float4 w0 = *(const float4*)(Wout + n0);
    const float4 w1 = *(const float4*)(Wout + NRES + n0);
    float p0 = cnt[0] * 0.1f * w0.x + cnt[1] * 0.1f * w0.y +
               cnt[2] * 0.1f * w0.z + cnt[3] * 0.1f * w0.w;
    float p1 = cnt[0] * 0.1f * w1.x + cnt[1] * 0.1f * w1.y +
               cnt[2] * 0.1f * w1.z + cnt[3] * 0.1f * w1.w;
    #pragma unroll
    for (int off = 32; off > 0; off >>= 1) {
        p0 += __shfl_down(p0, off);
        p1 += __shfl_down(p1, off);
    }
    if (lane == 0) { red[0][wid] = p0; red[1][wid] = p1; }
    __syncthreads();
    if (tid == 0) {
        float q0 = 0.f, q1 = 0.f;
        #pragma unroll
        for (int i = 0; i < 8; ++i) { q0 += red[0][i]; q1 += red[1][i]; }
        const size_t loff = (size_t)SEQ * BATCH * NRES;
        out[loff + b * 2 + 0] = q0;
        out[loff + b * 2 + 1] = q1;
    }
}

extern "C" void kernel_launch(void* const* d_in, const int* in_sizes, int n_in,
                              void* d_out, int out_size, void* d_ws, size_t ws_size,
                              hipStream_t stream) {
    const float* x    = (const float*)d_in[0];
    const float* W    = (const float*)d_in[1];
    const float* Win  = (const float*)d_in[2];
    const float* Wout = (const float*)d_in[3];
    float* out = (float*)d_out;
    hipLaunchKernelGGL(snn_reservoir_kernel, dim3(BATCH), dim3(NTHR), 0, stream,
                       x, W, Win, Wout, out);
}